// Round 1
// baseline (296.512 us; speedup 1.0000x reference)
//
#include <hip/hip_runtime.h>
#include <hip/hip_bf16.h>
#include <stdint.h>

// ---------------------------------------------------------------------------
// NonLocalBlock2D: B=16, C=512, I=256, H=W=56, N=3136 (padded to 3200)
//   P[b,0:256,:]   = g  = g_w  @ x[b] + g_b
//   P[b,256:512,:] = th = th_w @ x[b] + th_b
//   P[b,512:768,:] = ph = ph_w @ x[b] + ph_b
//   MT[b,i,j] = (1/N) * sum_n g[b,i,n]*ph[b,j,n]     ( == M[b,j,i] )
//   y[b,i,n]  = sum_j MT[b,i,j]*th[b,j,n]
//   out       = x + W_w @ y + W_b
// All GEMMs: bf16 MFMA 16x16x32, f32 accum. 128x128 tile, 4 waves (2x2),
// each wave 64x64 = 4x4 fragments. BK=32. LDS row stride 36 u16 (conflict pad).
// Workspace layout (bytes):
//   P   @ 0          : 16*768*3200*2  = 78,643,200
//   Mf  @ 78643200   : 4*16*256*256*4 = 16,777,216   (split-K partials)
//   MT  @ 95420416   : 16*256*256*2   =  2,097,152
//   Y   @ 97517568   : 16*256*3200*2  = 26,214,400
//   W3  @ 123731968  : 768*512*2      =    786,432
//   Ww  @ 124518400  : 512*256*2      =    262,144
//   total ~124.8 MB
// ---------------------------------------------------------------------------

typedef __attribute__((ext_vector_type(8))) short short8;    // 8 x bf16 frag
typedef __attribute__((ext_vector_type(4))) float f32x4;
typedef __attribute__((ext_vector_type(8))) unsigned short us8;

#define NPAD 3200
#define NSP  3136
#define LSTR 36   // LDS row stride in ushorts

__device__ inline unsigned short f2b(float f) {
  union { float f; uint32_t u; } c; c.f = f;
  uint32_t u = c.u;
  uint32_t r = (u + 0x7fffu + ((u >> 16) & 1u)) >> 16;
  return (unsigned short)r;
}

__device__ inline short8 lds_frag(const unsigned short* p) {
  // two 8B LDS reads (addr is 8B aligned: row*72 + {0,16,32,48})
  uint2 lo = *reinterpret_cast<const uint2*>(p);
  uint2 hi = *reinterpret_cast<const uint2*>(p + 4);
  union { uint32_t u[4]; short8 v; } cv;
  cv.u[0] = lo.x; cv.u[1] = lo.y; cv.u[2] = hi.x; cv.u[3] = hi.y;
  return cv.v;
}

// MODE 1: A=W3[768][512],  B=x f32 [512][3136] (NN, guard n<3136), C=P bf16 (+bias, pad->0)
// MODE 2: A=P g rows,      B=P ph rows (NT),  C=Mf f32 partial (split-K by blockIdx.z&3)
// MODE 3: A=MT[256][256],  B=P th rows (NN),  C=Y bf16
// MODE 4: A=Ww[512][256],  B=Y (NN),          C=d_out f32 (+x +W_b, guard n<3136)
template<int MODE>
__global__ __launch_bounds__(256) void nlb_gemm(
    const unsigned short* __restrict__ Abase,
    const unsigned short* __restrict__ Bb16,
    const float* __restrict__ Bf32,
    void* __restrict__ Cbase,
    const float* __restrict__ gb, const float* __restrict__ tb,
    const float* __restrict__ pb,
    const float* __restrict__ xres, const float* __restrict__ wb)
{
  const int bz = blockIdx.z;
  int b, kbeg, kend, lda, ldb;
  const unsigned short* A;
  const unsigned short* B16 = nullptr;
  const float* B32 = nullptr;

  if constexpr (MODE == 1) {
    b = bz; lda = 512; ldb = NSP;
    A = Abase;
    B32 = Bf32 + (size_t)b * 512 * NSP;
    kbeg = 0; kend = 512;
  } else if constexpr (MODE == 2) {
    b = bz >> 2; int kc = bz & 3;
    lda = NPAD; ldb = NPAD;
    A   = Abase + (size_t)b * 768 * NPAD;                      // g rows 0..255
    B16 = Abase + (size_t)b * 768 * NPAD + (size_t)512 * NPAD; // ph rows
    kbeg = kc * 800; kend = kbeg + 800;
  } else if constexpr (MODE == 3) {
    b = bz; lda = 256; ldb = NPAD;
    A = Abase + (size_t)b * 256 * 256;                         // MT
    B16 = Bb16 + (size_t)b * 768 * NPAD + (size_t)256 * NPAD;  // th rows
    kbeg = 0; kend = 256;
  } else {
    b = bz; lda = 256; ldb = NPAD;
    A = Abase;                                                 // Ww
    B16 = Bb16 + (size_t)b * 256 * NPAD;                       // y
    kbeg = 0; kend = 256;
  }

  const int m0 = blockIdx.x * 128;
  const int n0 = blockIdx.y * 128;
  const int tid = threadIdx.x;
  const int lane = tid & 63;
  const int wid = tid >> 6;
  const int wr = wid >> 1, wc = wid & 1;
  const int lrow = lane & 15;
  const int khalf = lane >> 4;
  const int kof = khalf * 8;

  __shared__ unsigned short As[128 * LSTR];
  __shared__ unsigned short Bs[128 * LSTR];

  f32x4 acc[4][4];
#pragma unroll
  for (int i = 0; i < 4; ++i)
#pragma unroll
    for (int j = 0; j < 4; ++j) acc[i][j] = f32x4{0.f, 0.f, 0.f, 0.f};

  for (int k0 = kbeg; k0 < kend; k0 += 32) {
    // ---- stage A tile [128 rows][32 k] (A is K-contiguous row-major bf16)
#pragma unroll
    for (int it = 0; it < 2; ++it) {
      int idx = it * 256 + tid;
      int r = idx >> 2;
      int kc = (idx & 3) * 8;
      us8 v = *reinterpret_cast<const us8*>(A + (size_t)(m0 + r) * lda + k0 + kc);
      union { us8 s; uint2 d[2]; } cv; cv.s = v;
      *reinterpret_cast<uint2*>(&As[r * LSTR + kc])     = cv.d[0];
      *reinterpret_cast<uint2*>(&As[r * LSTR + kc + 4]) = cv.d[1];
    }
    // ---- stage B tile -> Bs[n][k]
    if constexpr (MODE == 2) {
      // NT: B rows are K-contiguous, same as A staging
#pragma unroll
      for (int it = 0; it < 2; ++it) {
        int idx = it * 256 + tid;
        int r = idx >> 2;
        int kc = (idx & 3) * 8;
        us8 v = *reinterpret_cast<const us8*>(B16 + (size_t)(n0 + r) * ldb + k0 + kc);
        union { us8 s; uint2 d[2]; } cv; cv.s = v;
        *reinterpret_cast<uint2*>(&Bs[r * LSTR + kc])     = cv.d[0];
        *reinterpret_cast<uint2*>(&Bs[r * LSTR + kc + 4]) = cv.d[1];
      }
    } else if constexpr (MODE == 1) {
      // NN f32 source with n-guard; transpose via packed b32 writes
      int c4 = tid & 31;       // n group of 4
      int kk = tid >> 5;       // 0..7
      int ncol = n0 + c4 * 4;
      bool ok = ncol < NSP;
#pragma unroll
      for (int it = 0; it < 2; ++it) {
        int krow = k0 + it * 16 + 2 * kk;
        f32x4 r0 = {0.f, 0.f, 0.f, 0.f}, r1 = {0.f, 0.f, 0.f, 0.f};
        if (ok) {
          r0 = *reinterpret_cast<const f32x4*>(B32 + (size_t)krow * ldb + ncol);
          r1 = *reinterpret_cast<const f32x4*>(B32 + (size_t)(krow + 1) * ldb + ncol);
        }
#pragma unroll
        for (int j = 0; j < 4; ++j) {
          uint32_t u = (uint32_t)f2b(r0[j]) | ((uint32_t)f2b(r1[j]) << 16);
          *reinterpret_cast<uint32_t*>(&Bs[(c4 * 4 + j) * LSTR + it * 16 + 2 * kk]) = u;
        }
      }
    } else {
      // NN bf16 source (padded buffers, no guard)
      int c8 = tid & 15;       // n group of 8
      int kk = tid >> 4;       // 0..15
      const unsigned short* p = B16 + (size_t)(k0 + 2 * kk) * ldb + n0 + c8 * 8;
      us8 r0 = *reinterpret_cast<const us8*>(p);
      us8 r1 = *reinterpret_cast<const us8*>(p + ldb);
#pragma unroll
      for (int j = 0; j < 8; ++j) {
        uint32_t u = (uint32_t)r0[j] | ((uint32_t)r1[j] << 16);
        *reinterpret_cast<uint32_t*>(&Bs[(c8 * 8 + j) * LSTR + 2 * kk]) = u;
      }
    }
    __syncthreads();

    short8 af[4], bfr[4];
#pragma unroll
    for (int m = 0; m < 4; ++m)
      af[m] = lds_frag(&As[(wr * 64 + m * 16 + lrow) * LSTR + kof]);
#pragma unroll
    for (int n = 0; n < 4; ++n)
      bfr[n] = lds_frag(&Bs[(wc * 64 + n * 16 + lrow) * LSTR + kof]);
#pragma unroll
    for (int m = 0; m < 4; ++m)
#pragma unroll
      for (int n = 0; n < 4; ++n)
        acc[m][n] = __builtin_amdgcn_mfma_f32_16x16x32_bf16(af[m], bfr[n], acc[m][n], 0, 0, 0);
    __syncthreads();
  }

  // ---- epilogue.  D layout: col = lane&15, row = (lane>>4)*4 + reg
#pragma unroll
  for (int m = 0; m < 4; ++m) {
    int rbase = m0 + wr * 64 + m * 16 + khalf * 4;
#pragma unroll
    for (int n = 0; n < 4; ++n) {
      int gcol = n0 + wc * 64 + n * 16 + lrow;
#pragma unroll
      for (int r = 0; r < 4; ++r) {
        float v = acc[m][n][r];
        int grow = rbase + r;
        if constexpr (MODE == 1) {
          float bias = (grow < 256) ? gb[grow]
                     : (grow < 512) ? tb[grow - 256] : pb[grow - 512];
          unsigned short o = (gcol < NSP) ? f2b(v + bias) : (unsigned short)0;
          reinterpret_cast<unsigned short*>(Cbase)
              [(size_t)b * 768 * NPAD + (size_t)grow * NPAD + gcol] = o;
        } else if constexpr (MODE == 2) {
          int kc = bz & 3;
          reinterpret_cast<float*>(Cbase)
              [((size_t)kc * 16 + b) * 65536 + grow * 256 + gcol] = v;
        } else if constexpr (MODE == 3) {
          reinterpret_cast<unsigned short*>(Cbase)
              [(size_t)b * 256 * NPAD + (size_t)grow * NPAD + gcol] = f2b(v);
        } else {
          if (gcol < NSP) {
            size_t o = (size_t)grow * NSP + gcol;
            reinterpret_cast<float*>(Cbase)[(size_t)b * 512 * NSP + o] =
                v + wb[grow] + xres[(size_t)b * 512 * NSP + o];
          }
        }
      }
    }
  }
}

__global__ __launch_bounds__(256) void prep_weights(
    const float* __restrict__ g_w, const float* __restrict__ th_w,
    const float* __restrict__ ph_w, const float* __restrict__ W_w,
    unsigned short* __restrict__ W3, unsigned short* __restrict__ Ww)
{
  int i = blockIdx.x * 256 + threadIdx.x;
  if (i < 768 * 512) {
    int row = i / 512, col = i - row * 512;
    const float* src = (row < 256) ? g_w : (row < 512) ? th_w : ph_w;
    W3[i] = f2b(src[(row & 255) * 512 + col]);
  } else {
    int j = i - 768 * 512;
    if (j < 512 * 256) Ww[j] = f2b(W_w[j]);
  }
}

__global__ __launch_bounds__(256) void cvt_M(
    const float* __restrict__ Mf, unsigned short* __restrict__ MT)
{
  int i = blockIdx.x * 256 + threadIdx.x;      // < 16*256*256 = 1048576
  const int SL = 16 * 256 * 256;
  float s = Mf[i] + Mf[SL + i] + Mf[2 * SL + i] + Mf[3 * SL + i];
  MT[i] = f2b(s * (1.0f / 3136.0f));
}

extern "C" void kernel_launch(void* const* d_in, const int* in_sizes, int n_in,
                              void* d_out, int out_size, void* d_ws, size_t ws_size,
                              hipStream_t stream) {
  const float* x    = (const float*)d_in[0];
  const float* g_w  = (const float*)d_in[1];
  const float* g_b  = (const float*)d_in[2];
  const float* th_w = (const float*)d_in[3];
  const float* th_b = (const float*)d_in[4];
  const float* ph_w = (const float*)d_in[5];
  const float* ph_b = (const float*)d_in[6];
  const float* W_w  = (const float*)d_in[7];
  const float* W_b  = (const float*)d_in[8];

  char* ws = (char*)d_ws;
  unsigned short* P  = (unsigned short*)(ws + 0);
  float*          Mf = (float*)(ws + 78643200);
  unsigned short* MT = (unsigned short*)(ws + 95420416);
  unsigned short* Y  = (unsigned short*)(ws + 97517568);
  unsigned short* W3 = (unsigned short*)(ws + 123731968);
  unsigned short* Ww = (unsigned short*)(ws + 124518400);

  prep_weights<<<2048, 256, 0, stream>>>(g_w, th_w, ph_w, W_w, W3, Ww);

  // stage 1: P = W3 @ x + bias   (M=768, N=3136->3200, K=512)
  nlb_gemm<1><<<dim3(6, 25, 16), 256, 0, stream>>>(
      W3, nullptr, x, P, g_b, th_b, ph_b, nullptr, nullptr);

  // stage 2: Mf partials = g . ph^T  (M=256, N=256, K=3200, split-K x4)
  nlb_gemm<2><<<dim3(2, 2, 64), 256, 0, stream>>>(
      P, nullptr, nullptr, Mf, nullptr, nullptr, nullptr, nullptr, nullptr);

  cvt_M<<<4096, 256, 0, stream>>>(Mf, MT);

  // stage 3: Y = MT @ th   (M=256, N=3200, K=256)
  nlb_gemm<3><<<dim3(2, 25, 16), 256, 0, stream>>>(
      MT, P, nullptr, Y, nullptr, nullptr, nullptr, nullptr, nullptr);

  // stage 4: out = x + Ww @ Y + W_b   (M=512, N=3136, K=256)
  nlb_gemm<4><<<dim3(4, 25, 16), 256, 0, stream>>>(
      Ww, Y, nullptr, d_out, nullptr, nullptr, nullptr, x, W_b);
}

// Round 2
// 242.848 us; speedup vs baseline: 1.2210x; 1.2210x over previous
//
#include <hip/hip_runtime.h>
#include <stdint.h>

// ---------------------------------------------------------------------------
// NonLocalBlock2D  B=16, C=512, I=256, N=3136 (pad 3200). All-NT bf16 GEMMs.
//   xb   [b][3200][512]  = x^T (bf16, rows >=3136 zero)
//   Pgp  [b][512][3200]  rows 0..255 = g = g_w@x+g_b ; rows 256..511 = ph
//   thT  [b][3200][256]  = (th_w@x+th_b)^T
//   MT   [b][256][256]   MT[i][j] = (1/N) sum_n g[i,n] ph[j,n]
//   yT   [b][3200][256]  yT[n][i] = sum_j thT[n,j] MT[i,j]
//   out  = x + W_w@y + W_b
// GEMM: 128x128 tile, 4 waves (2x2) x 64x64, BK=32, mfma_f32_16x16x32_bf16,
// global_load_lds width=16 staging into linear LDS [128][32] (m97 structure).
// Workspace (bytes):
//   xb  @ 0          : 52,428,800      (dead after G1b)
//   Mf  @ 0          : 5*16*65536*4 = 20,971,520   (aliases xb)
//   MT  @ 20971520   : 2,097,152                    (aliases xb)
//   yT  @ 23068672   : 26,214,400                   (aliases xb)
//   Pgp @ 52428800   : 52,428,800
//   thT @ 104857600  : 26,214,400
//   W2  @ 131072000  : 524,288
//   thw @ 131596288  : 262,144
//   Wwb @ 131858432  : 262,144
//   bias2 @ 132120576: 2,048          total ~132.1 MB
// ---------------------------------------------------------------------------

typedef __attribute__((ext_vector_type(8))) short short8;
typedef __attribute__((ext_vector_type(4))) float f32x4;
typedef __attribute__((ext_vector_type(8))) unsigned short us8;

#define NSP  3136
#define NPAD 3200

#define AS1(p) ((const __attribute__((address_space(1))) void*)(p))
#define AS3(p) ((__attribute__((address_space(3))) void*)(p))

__device__ inline unsigned short f2b(float f) {
  union { float f; uint32_t u; } c; c.f = f;
  uint32_t u = c.u;
  uint32_t r = (u + 0x7fffu + ((u >> 16) & 1u)) >> 16;
  return (unsigned short)r;
}

// MODE 1: Pgp = W2 .NT xb          (M=512, N=3200, K=512)  +bias2[row], col<NSP else 0
// MODE 5: thT = xb .NT thw         (M=3200, N=256, K=512)  +th_b[col]
// MODE 2: Mf  = g  .NT ph partials (M=256, N=256, K=3200 split 5x640) f32
// MODE 3: yT  = thT .NT MT         (M=3200, N=256, K=256)
// MODE 4: out = Wwb .NT yT + x + W_b (M=512, N=3200, K=256) col<NSP guard, f32
template<int MODE>
__global__ __launch_bounds__(256) void nt_gemm(
    const unsigned short* __restrict__ Abase,
    const unsigned short* __restrict__ Bbase,
    void* __restrict__ Cbase,
    const float* __restrict__ bias,
    const float* __restrict__ xres)
{
  const int bz = blockIdx.z;
  int b, kc = 0, kbeg, kend, lda, ldb;
  const unsigned short *A, *B;

  if constexpr (MODE == 1) {
    b = bz; A = Abase; B = Bbase + (size_t)b * NPAD * 512;
    lda = 512; ldb = 512; kbeg = 0; kend = 512;
  } else if constexpr (MODE == 5) {
    b = bz; A = Abase + (size_t)b * NPAD * 512; B = Bbase;
    lda = 512; ldb = 512; kbeg = 0; kend = 512;
  } else if constexpr (MODE == 2) {
    b = bz & 15; kc = bz >> 4;
    A = Abase + (size_t)b * 512 * NPAD;
    B = A + (size_t)256 * NPAD;
    lda = NPAD; ldb = NPAD; kbeg = kc * 640; kend = kbeg + 640;
  } else if constexpr (MODE == 3) {
    b = bz; A = Abase + (size_t)b * NPAD * 256; B = Bbase + (size_t)b * 65536;
    lda = 256; ldb = 256; kbeg = 0; kend = 256;
  } else {
    b = bz; A = Abase; B = Bbase + (size_t)b * NPAD * 256;
    lda = 256; ldb = 256; kbeg = 0; kend = 256;
  }

  const int m0 = blockIdx.x * 128;
  const int n0 = blockIdx.y * 128;
  const int tid = threadIdx.x;
  const int lane = tid & 63;
  const int wid = tid >> 6;
  const int wr = wid >> 1, wc = wid & 1;
  const int lrow = lane & 15;
  const int khalf = lane >> 4;
  const int kof = khalf * 8;
  const int rA  = lane >> 2;        // row within 16-row chunk
  const int kc8 = (lane & 3) * 8;   // k-offset within 32

  __shared__ unsigned short As[128 * 32];
  __shared__ unsigned short Bs[128 * 32];

  f32x4 acc[4][4];
#pragma unroll
  for (int i = 0; i < 4; ++i)
#pragma unroll
    for (int j = 0; j < 4; ++j) acc[i][j] = f32x4{0.f, 0.f, 0.f, 0.f};

  const unsigned short* pa0 = A + (size_t)(m0 + (wid * 2 + 0) * 16 + rA) * lda + kbeg + kc8;
  const unsigned short* pa1 = A + (size_t)(m0 + (wid * 2 + 1) * 16 + rA) * lda + kbeg + kc8;
  const unsigned short* pb0 = B + (size_t)(n0 + (wid * 2 + 0) * 16 + rA) * ldb + kbeg + kc8;
  const unsigned short* pb1 = B + (size_t)(n0 + (wid * 2 + 1) * 16 + rA) * ldb + kbeg + kc8;
  unsigned short* la0 = &As[(wid * 2 + 0) * 512];
  unsigned short* la1 = &As[(wid * 2 + 1) * 512];
  unsigned short* lb0 = &Bs[(wid * 2 + 0) * 512];
  unsigned short* lb1 = &Bs[(wid * 2 + 1) * 512];

  for (int k0 = kbeg; k0 < kend; k0 += 32) {
    __builtin_amdgcn_global_load_lds(AS1(pa0), AS3(la0), 16, 0, 0);
    __builtin_amdgcn_global_load_lds(AS1(pa1), AS3(la1), 16, 0, 0);
    __builtin_amdgcn_global_load_lds(AS1(pb0), AS3(lb0), 16, 0, 0);
    __builtin_amdgcn_global_load_lds(AS1(pb1), AS3(lb1), 16, 0, 0);
    pa0 += 32; pa1 += 32; pb0 += 32; pb1 += 32;
    __syncthreads();

    short8 af[4], bfv[4];
#pragma unroll
    for (int m = 0; m < 4; ++m)
      af[m] = *reinterpret_cast<const short8*>(&As[(wr * 64 + m * 16 + lrow) * 32 + kof]);
#pragma unroll
    for (int n = 0; n < 4; ++n)
      bfv[n] = *reinterpret_cast<const short8*>(&Bs[(wc * 64 + n * 16 + lrow) * 32 + kof]);
#pragma unroll
    for (int m = 0; m < 4; ++m)
#pragma unroll
      for (int n = 0; n < 4; ++n)
        acc[m][n] = __builtin_amdgcn_mfma_f32_16x16x32_bf16(af[m], bfv[n], acc[m][n], 0, 0, 0);
    __syncthreads();
  }

  // D layout: col = lane&15, row = (lane>>4)*4 + reg
#pragma unroll
  for (int m = 0; m < 4; ++m) {
    int rbase = m0 + wr * 64 + m * 16 + khalf * 4;
#pragma unroll
    for (int n = 0; n < 4; ++n) {
      int gcol = n0 + wc * 64 + n * 16 + lrow;
#pragma unroll
      for (int r = 0; r < 4; ++r) {
        float v = acc[m][n][r];
        int grow = rbase + r;
        if constexpr (MODE == 1) {
          unsigned short o = (gcol < NSP) ? f2b(v + bias[grow]) : (unsigned short)0;
          reinterpret_cast<unsigned short*>(Cbase)
              [(size_t)b * 512 * NPAD + (size_t)grow * NPAD + gcol] = o;
        } else if constexpr (MODE == 5) {
          reinterpret_cast<unsigned short*>(Cbase)
              [(size_t)b * NPAD * 256 + (size_t)grow * 256 + gcol] = f2b(v + bias[gcol]);
        } else if constexpr (MODE == 2) {
          reinterpret_cast<float*>(Cbase)
              [((size_t)kc * 16 + b) * 65536 + grow * 256 + gcol] = v;
        } else if constexpr (MODE == 3) {
          reinterpret_cast<unsigned short*>(Cbase)
              [(size_t)b * NPAD * 256 + (size_t)grow * 256 + gcol] = f2b(v);
        } else {
          if (gcol < NSP) {
            size_t o = ((size_t)b * 512 + grow) * NSP + gcol;
            reinterpret_cast<float*>(Cbase)[o] = v + bias[grow] + xres[o];
          }
        }
      }
    }
  }
}

// x [b][512][3136] f32  ->  xb [b][3200][512] bf16 (rows >=3136 zero)
__global__ __launch_bounds__(256) void transp_x(const float* __restrict__ x,
                                                unsigned short* __restrict__ xb)
{
  const int nt = blockIdx.x, ct = blockIdx.y, b = blockIdx.z;
  const int t = threadIdx.x;
  const int n0 = nt * 64, c0 = ct * 64;
  __shared__ float Ls[64 * 65];

  if (nt == 49) {  // rows 3136..3199: all zero (3136 == 49*64)
    us8 z = {0, 0, 0, 0, 0, 0, 0, 0};
#pragma unroll
    for (int it = 0; it < 2; ++it) {
      int idx = it * 256 + t; int nl = idx >> 3, cc = idx & 7;
      *reinterpret_cast<us8*>(&xb[((size_t)b * NPAD + n0 + nl) * 512 + c0 + cc * 8]) = z;
    }
    return;
  }
  const float* xs = x + (size_t)b * 512 * NSP;
#pragma unroll
  for (int p = 0; p < 4; ++p) {
    int cl = p * 16 + (t >> 4);
    int nl = (t & 15) * 4;
    f32x4 v = *reinterpret_cast<const f32x4*>(&xs[(size_t)(c0 + cl) * NSP + n0 + nl]);
    Ls[cl * 65 + nl + 0] = v[0];
    Ls[cl * 65 + nl + 1] = v[1];
    Ls[cl * 65 + nl + 2] = v[2];
    Ls[cl * 65 + nl + 3] = v[3];
  }
  __syncthreads();
#pragma unroll
  for (int it = 0; it < 2; ++it) {
    int idx = it * 256 + t; int nl = idx >> 3, cc = idx & 7;
    us8 o;
#pragma unroll
    for (int j = 0; j < 8; ++j) o[j] = f2b(Ls[(cc * 8 + j) * 65 + nl]);
    *reinterpret_cast<us8*>(&xb[((size_t)b * NPAD + n0 + nl) * 512 + c0 + cc * 8]) = o;
  }
}

__global__ __launch_bounds__(256) void prep_weights(
    const float* __restrict__ g_w, const float* __restrict__ ph_w,
    const float* __restrict__ th_w, const float* __restrict__ W_w,
    const float* __restrict__ g_b, const float* __restrict__ ph_b,
    unsigned short* __restrict__ W2, unsigned short* __restrict__ thw,
    unsigned short* __restrict__ Wwb, float* __restrict__ bias2)
{
  int i = blockIdx.x * 256 + threadIdx.x;
  if (i < 262144) {
    W2[i] = f2b(i < 131072 ? g_w[i] : ph_w[i - 131072]);
  } else if (i < 393216) {
    thw[i - 262144] = f2b(th_w[i - 262144]);
  } else if (i < 524288) {
    Wwb[i - 393216] = f2b(W_w[i - 393216]);
  } else if (i < 524800) {
    int r = i - 524288;
    bias2[r] = r < 256 ? g_b[r] : ph_b[r - 256];
  }
}

__global__ __launch_bounds__(256) void cvt_M(const float* __restrict__ Mf,
                                             unsigned short* __restrict__ MT)
{
  int i = blockIdx.x * 256 + threadIdx.x;   // 16*256*256 = 1048576
  const int SL = 1048576;
  float s = 0.f;
#pragma unroll
  for (int k = 0; k < 5; ++k) s += Mf[(size_t)k * SL + i];
  MT[i] = f2b(s * (1.0f / 3136.0f));
}

extern "C" void kernel_launch(void* const* d_in, const int* in_sizes, int n_in,
                              void* d_out, int out_size, void* d_ws, size_t ws_size,
                              hipStream_t stream) {
  const float* x    = (const float*)d_in[0];
  const float* g_w  = (const float*)d_in[1];
  const float* g_b  = (const float*)d_in[2];
  const float* th_w = (const float*)d_in[3];
  const float* th_b = (const float*)d_in[4];
  const float* ph_w = (const float*)d_in[5];
  const float* ph_b = (const float*)d_in[6];
  const float* W_w  = (const float*)d_in[7];
  const float* W_b  = (const float*)d_in[8];

  char* ws = (char*)d_ws;
  unsigned short* xb  = (unsigned short*)(ws + 0);
  float*          Mf  = (float*)(ws + 0);              // aliases xb (dead)
  unsigned short* MT  = (unsigned short*)(ws + 20971520);
  unsigned short* yT  = (unsigned short*)(ws + 23068672);
  unsigned short* Pgp = (unsigned short*)(ws + 52428800);
  unsigned short* thT = (unsigned short*)(ws + 104857600);
  unsigned short* W2  = (unsigned short*)(ws + 131072000);
  unsigned short* thw = (unsigned short*)(ws + 131596288);
  unsigned short* Wwb = (unsigned short*)(ws + 131858432);
  float*        bias2 = (float*)(ws + 132120576);

  prep_weights<<<2051, 256, 0, stream>>>(g_w, ph_w, th_w, W_w, g_b, ph_b,
                                         W2, thw, Wwb, bias2);
  transp_x<<<dim3(50, 8, 16), 256, 0, stream>>>(x, xb);

  // G1a: Pgp = W2 .NT xb  (+bias2)
  nt_gemm<1><<<dim3(4, 25, 16), 256, 0, stream>>>(W2, xb, Pgp, bias2, nullptr);
  // G1b: thT = xb .NT thw (+th_b per col)
  nt_gemm<5><<<dim3(25, 2, 16), 256, 0, stream>>>(xb, thw, thT, th_b, nullptr);
  // G2: Mf partials = g .NT ph  (split-K 5x640)
  nt_gemm<2><<<dim3(2, 2, 80), 256, 0, stream>>>(Pgp, nullptr, Mf, nullptr, nullptr);
  cvt_M<<<4096, 256, 0, stream>>>(Mf, MT);
  // G3: yT = thT .NT MT
  nt_gemm<3><<<dim3(25, 2, 16), 256, 0, stream>>>(thT, MT, yT, nullptr, nullptr);
  // G4: out = Wwb .NT yT + x + W_b
  nt_gemm<4><<<dim3(4, 25, 16), 256, 0, stream>>>(Wwb, yT, d_out, W_b, x);
}

// Round 3
// 219.789 us; speedup vs baseline: 1.3491x; 1.1049x over previous
//
#include <hip/hip_runtime.h>
#include <stdint.h>

// ---------------------------------------------------------------------------
// NonLocalBlock2D  B=16, C=512, I=256, N=3136 (pad 3200). All-NT bf16 GEMMs.
// Chain:
//   xb  [b][3200][512] = x^T bf16 (rows>=3136 zero)
//   P   [b][768][3200] = W3 .NT xb + bias3   (rows: g[0,256) ph[256,512) th[512,768))
//   thT [b][3200][256] = transpose of P th rows
//   MT2 [b][256][256]  : MT2[j][i] = (1/N) sum_n ph[j,n] g[i,n]   (split-K 5x640)
//   U   [b][512][256]  : U[c][j] = sum_i Ww[c][i] MT2[j][i]       ( = Ww @ M )
//   out = U .NT thT + x + W_b      (reassociated: Ww@(M@th) == (Ww@M)@th)
// GEMM: 128x128 tile, 4 waves (2x2) x 64x64, BK=32, mfma_f32_16x16x32_bf16,
// global_load_lds width=16, 2-phase dbuf LDS with counted vmcnt(4) (T3/T4),
// bijective XCD swizzle (all grids % 8 == 0).
// Workspace (bytes):
//   xb  @ 0         : 52,428,800   (dead after G1)
//   thT @ 0         : 26,214,400   (aliases xb, written after G1)
//   Mf2 @ 26214400  : 20,971,520   (5 split-K partials, f32)
//   MT2 @ 47185920  :  2,097,152
//   P   @ 52428800  : 78,643,200   (dead after G2+transpose)
//   U   @ 52428800  :  4,194,304   (aliases P head; written after G2/transpose)
//   W3b @ 131072000 :    786,432
//   Wwb @ 131858432 :    262,144
//   bias3 @ 132120576:     3,072   total ~132.1 MB
// ---------------------------------------------------------------------------

typedef __attribute__((ext_vector_type(8))) short short8;
typedef __attribute__((ext_vector_type(4))) float f32x4;
typedef __attribute__((ext_vector_type(8))) unsigned short us8;

#define NSP  3136
#define NPAD 3200

#define AS1(p) ((const __attribute__((address_space(1))) void*)(p))
#define AS3(p) ((__attribute__((address_space(3))) void*)(p))

__device__ inline unsigned short f2b(float f) {
  union { float f; uint32_t u; } c; c.f = f;
  uint32_t u = c.u;
  uint32_t r = (u + 0x7fffu + ((u >> 16) & 1u)) >> 16;
  return (unsigned short)r;
}

// MODE 1: P   = W3  .NT xb   (M=768, N=3200, K=512)  +bias3[row], col<NSP else 0
// MODE 2: Mf2 = ph  .NT g    (M=256, N=256, K=3200 split 5x640) f32 partials
// MODE 6: U   = Wwb .NT MT2  (M=512, N=256, K=256) bf16
// MODE 4: out = U   .NT thT + x + W_b (M=512, N=3200, K=256) col<NSP guard, f32
template<int MODE>
__global__ __launch_bounds__(256) void nt_gemm(
    const unsigned short* __restrict__ Abase,
    const unsigned short* __restrict__ Bbase,
    void* __restrict__ Cbase,
    const float* __restrict__ bias,
    const float* __restrict__ xres)
{
  // bijective XCD swizzle over flattened block id (nwg % 8 == 0 for all grids)
  const int nwg = gridDim.x * gridDim.y * gridDim.z;
  int flat = blockIdx.x + gridDim.x * (blockIdx.y + gridDim.y * blockIdx.z);
  const int q = nwg >> 3;
  int swz = (flat & 7) * q + (flat >> 3);
  const int bx = swz % gridDim.x; int tmp = swz / gridDim.x;
  const int by = tmp % gridDim.y;
  const int bz = tmp / gridDim.y;

  int b, kc = 0, kbeg, kend, lda, ldb;
  const unsigned short *A, *B;

  if constexpr (MODE == 1) {
    b = bz; A = Abase; B = Bbase + (size_t)b * NPAD * 512;
    lda = 512; ldb = 512; kbeg = 0; kend = 512;
  } else if constexpr (MODE == 2) {
    b = bz & 15; kc = bz >> 4;
    A = Abase + (size_t)b * 768 * NPAD + (size_t)256 * NPAD;  // ph rows
    B = Abase + (size_t)b * 768 * NPAD;                       // g rows
    lda = NPAD; ldb = NPAD; kbeg = kc * 640; kend = kbeg + 640;
  } else if constexpr (MODE == 6) {
    b = bz; A = Abase; B = Bbase + (size_t)b * 65536;
    lda = 256; ldb = 256; kbeg = 0; kend = 256;
  } else {
    b = bz; A = Abase + (size_t)b * 131072; B = Bbase + (size_t)b * NPAD * 256;
    lda = 256; ldb = 256; kbeg = 0; kend = 256;
  }

  const int m0 = bx * 128;
  const int n0 = by * 128;
  const int tid = threadIdx.x;
  const int lane = tid & 63;
  const int wid = tid >> 6;
  const int wr = wid >> 1, wc = wid & 1;
  const int lrow = lane & 15;
  const int khalf = lane >> 4;
  const int kof = khalf * 8;
  const int rA  = lane >> 2;        // row within 16-row chunk
  const int kc8 = (lane & 3) * 8;   // k-offset within 32

  __shared__ unsigned short As[2][128 * 32];
  __shared__ unsigned short Bs[2][128 * 32];

  f32x4 acc[4][4];
#pragma unroll
  for (int i = 0; i < 4; ++i)
#pragma unroll
    for (int j = 0; j < 4; ++j) acc[i][j] = f32x4{0.f, 0.f, 0.f, 0.f};

  const unsigned short* pa0 = A + (size_t)(m0 + (wid * 2 + 0) * 16 + rA) * lda + kbeg + kc8;
  const unsigned short* pa1 = A + (size_t)(m0 + (wid * 2 + 1) * 16 + rA) * lda + kbeg + kc8;
  const unsigned short* pb0 = B + (size_t)(n0 + (wid * 2 + 0) * 16 + rA) * ldb + kbeg + kc8;
  const unsigned short* pb1 = B + (size_t)(n0 + (wid * 2 + 1) * 16 + rA) * ldb + kbeg + kc8;
  const int la0 = (wid * 2 + 0) * 512;
  const int la1 = (wid * 2 + 1) * 512;

#define STAGE(bufi) do {                                                        \
    __builtin_amdgcn_global_load_lds(AS1(pa0), AS3(&As[bufi][la0]), 16, 0, 0);  \
    __builtin_amdgcn_global_load_lds(AS1(pa1), AS3(&As[bufi][la1]), 16, 0, 0);  \
    __builtin_amdgcn_global_load_lds(AS1(pb0), AS3(&Bs[bufi][la0]), 16, 0, 0);  \
    __builtin_amdgcn_global_load_lds(AS1(pb1), AS3(&Bs[bufi][la1]), 16, 0, 0);  \
    pa0 += 32; pa1 += 32; pb0 += 32; pb1 += 32;                                 \
  } while (0)

  // pin any compiler-preloaded VMEM before the counted window
  asm volatile("s_waitcnt vmcnt(0)" ::: "memory");
  STAGE(0);

  const int nsteps = (kend - kbeg) >> 5;
  for (int t = 0; t < nsteps; ++t) {
    const int cur = t & 1;
    if (t + 1 < nsteps) {
      STAGE(cur ^ 1);
      asm volatile("s_waitcnt vmcnt(4)" ::: "memory");  // cur's 4 landed, next's 4 in flight
    } else {
      asm volatile("s_waitcnt vmcnt(0)" ::: "memory");
    }
    __builtin_amdgcn_s_barrier();
    __builtin_amdgcn_sched_barrier(0);

    short8 af[4], bfv[4];
#pragma unroll
    for (int m = 0; m < 4; ++m)
      af[m] = *reinterpret_cast<const short8*>(&As[cur][(wr * 64 + m * 16 + lrow) * 32 + kof]);
#pragma unroll
    for (int n = 0; n < 4; ++n)
      bfv[n] = *reinterpret_cast<const short8*>(&Bs[cur][(wc * 64 + n * 16 + lrow) * 32 + kof]);
#pragma unroll
    for (int m = 0; m < 4; ++m)
#pragma unroll
      for (int n = 0; n < 4; ++n)
        acc[m][n] = __builtin_amdgcn_mfma_f32_16x16x32_bf16(af[m], bfv[n], acc[m][n], 0, 0, 0);
    __builtin_amdgcn_s_barrier();   // all waves done reading buf[cur] before overwrite
  }
#undef STAGE

  // D layout: col = lane&15, row = (lane>>4)*4 + reg
#pragma unroll
  for (int m = 0; m < 4; ++m) {
    int rbase = m0 + wr * 64 + m * 16 + khalf * 4;
#pragma unroll
    for (int n = 0; n < 4; ++n) {
      int gcol = n0 + wc * 64 + n * 16 + lrow;
#pragma unroll
      for (int r = 0; r < 4; ++r) {
        float v = acc[m][n][r];
        int grow = rbase + r;
        if constexpr (MODE == 1) {
          unsigned short o = (gcol < NSP) ? f2b(v + bias[grow]) : (unsigned short)0;
          reinterpret_cast<unsigned short*>(Cbase)
              [(size_t)b * 768 * NPAD + (size_t)grow * NPAD + gcol] = o;
        } else if constexpr (MODE == 2) {
          reinterpret_cast<float*>(Cbase)
              [((size_t)kc * 16 + b) * 65536 + grow * 256 + gcol] = v;
        } else if constexpr (MODE == 6) {
          reinterpret_cast<unsigned short*>(Cbase)
              [(size_t)b * 131072 + grow * 256 + gcol] = f2b(v);
        } else {
          if (gcol < NSP) {
            size_t o = ((size_t)b * 512 + grow) * NSP + gcol;
            reinterpret_cast<float*>(Cbase)[o] = v + bias[grow] + xres[o];
          }
        }
      }
    }
  }
}

// x [b][512][3136] f32  ->  xb [b][3200][512] bf16 (rows >=3136 zero)
__global__ __launch_bounds__(256) void transp_x(const float* __restrict__ x,
                                                unsigned short* __restrict__ xb)
{
  const int nt = blockIdx.x, ct = blockIdx.y, b = blockIdx.z;
  const int t = threadIdx.x;
  const int n0 = nt * 64, c0 = ct * 64;
  __shared__ float Ls[64 * 65];

  if (nt == 49) {  // rows 3136..3199: all zero
    us8 z = {0, 0, 0, 0, 0, 0, 0, 0};
#pragma unroll
    for (int it = 0; it < 2; ++it) {
      int idx = it * 256 + t; int nl = idx >> 3, cc = idx & 7;
      *reinterpret_cast<us8*>(&xb[((size_t)b * NPAD + n0 + nl) * 512 + c0 + cc * 8]) = z;
    }
    return;
  }
  const float* xs = x + (size_t)b * 512 * NSP;
#pragma unroll
  for (int p = 0; p < 4; ++p) {
    int cl = p * 16 + (t >> 4);
    int nl = (t & 15) * 4;
    f32x4 v = *reinterpret_cast<const f32x4*>(&xs[(size_t)(c0 + cl) * NSP + n0 + nl]);
    Ls[cl * 65 + nl + 0] = v[0];
    Ls[cl * 65 + nl + 1] = v[1];
    Ls[cl * 65 + nl + 2] = v[2];
    Ls[cl * 65 + nl + 3] = v[3];
  }
  __syncthreads();
#pragma unroll
  for (int it = 0; it < 2; ++it) {
    int idx = it * 256 + t; int nl = idx >> 3, cc = idx & 7;
    us8 o;
#pragma unroll
    for (int j = 0; j < 8; ++j) o[j] = f2b(Ls[(cc * 8 + j) * 65 + nl]);
    *reinterpret_cast<us8*>(&xb[((size_t)b * NPAD + n0 + nl) * 512 + c0 + cc * 8]) = o;
  }
}

// P th rows [b][512+j][n] (bf16) -> thT [b][n][j]
__global__ __launch_bounds__(256) void transp_th(const unsigned short* __restrict__ P,
                                                 unsigned short* __restrict__ thT)
{
  const int nt = blockIdx.x, jt = blockIdx.y, b = blockIdx.z;
  const int t = threadIdx.x;
  const int n0 = nt * 64, j0 = jt * 64;
  __shared__ unsigned short Ls[64 * 72];

  const unsigned short* src = P + ((size_t)b * 768 + 512 + j0) * NPAD + n0;
#pragma unroll
  for (int it = 0; it < 2; ++it) {
    int idx = it * 256 + t; int jl = idx >> 3, nc = (idx & 7) * 8;
    us8 v = *reinterpret_cast<const us8*>(&src[(size_t)jl * NPAD + nc]);
    *reinterpret_cast<us8*>(&Ls[jl * 72 + nc]) = v;
  }
  __syncthreads();
#pragma unroll
  for (int it = 0; it < 2; ++it) {
    int idx = it * 256 + t; int nl = idx >> 3, jc = (idx & 7) * 8;
    us8 o;
#pragma unroll
    for (int j = 0; j < 8; ++j) o[j] = Ls[(jc + j) * 72 + nl];
    *reinterpret_cast<us8*>(&thT[((size_t)b * NPAD + n0 + nl) * 256 + j0 + jc]) = o;
  }
}

__global__ __launch_bounds__(256) void prep_weights(
    const float* __restrict__ g_w, const float* __restrict__ ph_w,
    const float* __restrict__ th_w, const float* __restrict__ W_w,
    const float* __restrict__ g_b, const float* __restrict__ ph_b,
    const float* __restrict__ th_b,
    unsigned short* __restrict__ W3, unsigned short* __restrict__ Wwb,
    float* __restrict__ bias3)
{
  int i = blockIdx.x * 256 + threadIdx.x;
  if (i < 393216) {
    int row = i >> 9, col = i & 511;
    float v = (row < 256) ? g_w[row * 512 + col]
            : (row < 512) ? ph_w[(row - 256) * 512 + col]
                          : th_w[(row - 512) * 512 + col];
    W3[i] = f2b(v);
  } else if (i < 524288) {
    Wwb[i - 393216] = f2b(W_w[i - 393216]);
  } else if (i < 525056) {
    int r = i - 524288;
    bias3[r] = (r < 256) ? g_b[r] : (r < 512) ? ph_b[r - 256] : th_b[r - 512];
  }
}

__global__ __launch_bounds__(256) void cvt_M(const float* __restrict__ Mf,
                                             unsigned short* __restrict__ MT)
{
  int i = blockIdx.x * 256 + threadIdx.x;   // 16*256*256 = 1048576
  const int SL = 1048576;
  float s = 0.f;
#pragma unroll
  for (int k = 0; k < 5; ++k) s += Mf[(size_t)k * SL + i];
  MT[i] = f2b(s * (1.0f / 3136.0f));
}

extern "C" void kernel_launch(void* const* d_in, const int* in_sizes, int n_in,
                              void* d_out, int out_size, void* d_ws, size_t ws_size,
                              hipStream_t stream) {
  const float* x    = (const float*)d_in[0];
  const float* g_w  = (const float*)d_in[1];
  const float* g_b  = (const float*)d_in[2];
  const float* th_w = (const float*)d_in[3];
  const float* th_b = (const float*)d_in[4];
  const float* ph_w = (const float*)d_in[5];
  const float* ph_b = (const float*)d_in[6];
  const float* W_w  = (const float*)d_in[7];
  const float* W_b  = (const float*)d_in[8];

  char* ws = (char*)d_ws;
  unsigned short* xb   = (unsigned short*)(ws + 0);
  unsigned short* thT  = (unsigned short*)(ws + 0);          // aliases xb (dead after G1)
  float*          Mf2  = (float*)(ws + 26214400);
  unsigned short* MT2  = (unsigned short*)(ws + 47185920);
  unsigned short* P    = (unsigned short*)(ws + 52428800);
  unsigned short* U    = (unsigned short*)(ws + 52428800);   // aliases P head (P dead)
  unsigned short* W3   = (unsigned short*)(ws + 131072000);
  unsigned short* Wwb  = (unsigned short*)(ws + 131858432);
  float*          bias3 = (float*)(ws + 132120576);

  prep_weights<<<2052, 256, 0, stream>>>(g_w, ph_w, th_w, W_w, g_b, ph_b, th_b,
                                         W3, Wwb, bias3);
  transp_x<<<dim3(50, 8, 16), 256, 0, stream>>>(x, xb);

  // G1: P = W3 .NT xb (+bias3)   M=768, N=3200, K=512
  nt_gemm<1><<<dim3(6, 25, 16), 256, 0, stream>>>(W3, xb, P, bias3, nullptr);
  // thT = transpose(P th rows)
  transp_th<<<dim3(50, 4, 16), 256, 0, stream>>>(P, thT);
  // G2: Mf2 partials = ph .NT g  (split-K 5x640)
  nt_gemm<2><<<dim3(2, 2, 80), 256, 0, stream>>>(P, nullptr, Mf2, nullptr, nullptr);
  cvt_M<<<4096, 256, 0, stream>>>(Mf2, MT2);
  // GU: U = Wwb .NT MT2          M=512, N=256, K=256
  nt_gemm<6><<<dim3(4, 2, 16), 256, 0, stream>>>(Wwb, MT2, U, nullptr, nullptr);
  // G4: out = U .NT thT + x + W_b
  nt_gemm<4><<<dim3(4, 25, 16), 256, 0, stream>>>(U, thT, d_out, W_b, x);
}